// Round 6
// baseline (175.008 us; speedup 1.0000x reference)
//
#include <hip/hip_runtime.h>
#include <hip/hip_fp16.h>

// Composite loss: 0.16*MSE + 0.84*(1-SSIM), 16x3x512x512 f32, win=11 sigma=1.5
// Vertical-first streaming with ASYNC global->LDS staging:
//   block = full image width (512 cols) x OH=4 output rows
//   stage: 14 rows x 512 cols x {pred,targ} fp32 via global_load_lds (16B/lane,
//          wave-uniform LDS base + lane*16 linear layout), ONE vmcnt wait
//   phase A: bulk ds_read_b64 (28/thread) -> regs, barrier, vertical 11-tap
//            conv of 5 planes -> fp16 planes OVERWRITE staging LDS
//   phase B: 64 groups x 8 cols x 1 row/thread, aligned b128 LDS reads,
//            horizontal conv + SSIM map in fp32 registers
// LDS = 57344 B static (planes alias staging); 2 blocks/CU.

#define OH 4

__device__ __forceinline__ void gload16(const float* g, float* l)
{
    __builtin_amdgcn_global_load_lds(
        (const __attribute__((address_space(1))) void*)g,
        (__attribute__((address_space(3))) void*)l,
        16, 0, 0);
}

__global__ __launch_bounds__(256, 2) void ssim_fused(
    const float* __restrict__ pred, const float* __restrict__ targ,
    float* __restrict__ accum)
{
    __shared__ float sRaw[2 * 14 * 512];   // 57344 B; fp16 planes alias front

    // Normalized 11-tap Gaussian (sigma=1.5)
    const float wv[11] = {
        0.00102838f, 0.00759876f, 0.03600078f, 0.10936070f, 0.21300554f,
        0.26601173f,
        0.21300554f, 0.10936070f, 0.03600078f, 0.00759876f, 0.00102838f };

    const int tid = threadIdx.x;
    // XCD-aware swizzle: 6144 blocks = 8 XCDs * 768 contiguous
    const int bid = ((int)blockIdx.x & 7) * 768 + ((int)blockIdx.x >> 3);
    const int img = bid >> 7;             // 48 planes
    const int oy0 = (bid & 127) * OH;     // 128 row-strips
    const float* __restrict__ P = pred + (size_t)img * (512 * 512);
    const float* __restrict__ T = targ + (size_t)img * (512 * 512);

    // ---------------- async stage: 14 rows x {P,T} -> LDS -------------------
    {
        const int lane = tid & 63;
        const int w    = tid >> 6;        // wave 0..3
        const int half = w & 1;           // which 1KB half-row
        const int tens = w >> 1;          // 0: pred, 1: targ
        const float* gsrc = tens ? T : P;
        float* lbase = sRaw + tens * (14 * 512);
        #pragma unroll
        for (int k = 0; k < 14; ++k) {
            int gy = oy0 + k; if (gy > 511) gy = 511;   // clamped rows feed only masked outputs
            gload16(gsrc + gy * 512 + half * 256 + lane * 4,
                    lbase + k * 512 + half * 256);
        }
    }
    asm volatile("s_waitcnt vmcnt(0)" ::: "memory");
    __syncthreads();

    // ---------------- phase A: bulk LDS->reg, then vertical conv ------------
    const int c0 = tid * 2;

    float2 xr[14], yr[14];
    #pragma unroll
    for (int i = 0; i < 14; ++i) {
        xr[i] = *reinterpret_cast<const float2*>(sRaw + i * 512 + c0);
        yr[i] = *reinterpret_cast<const float2*>(sRaw + (14 + i) * 512 + c0);
    }
    __syncthreads();   // all raw reads done; planes may overwrite staging

    float acc[5][OH][2];
    #pragma unroll
    for (int p = 0; p < 5; ++p)
        #pragma unroll
        for (int j = 0; j < OH; ++j) { acc[p][j][0] = 0.f; acc[p][j][1] = 0.f; }

    float mse_acc = 0.f;

    #pragma unroll
    for (int i = 0; i < 14; ++i) {
        const float x0 = fminf(fmaxf(xr[i].x, 0.f), 1.f);
        const float x1 = fminf(fmaxf(xr[i].y, 0.f), 1.f);
        const float y0 = fminf(fmaxf(yr[i].x, 0.f), 1.f);
        const float y1 = fminf(fmaxf(yr[i].y, 0.f), 1.f);
        if (i < OH) {   // this block's disjoint MSE rows
            const float d0 = x0 - y0, d1 = x1 - y1;
            mse_acc += d0 * d0 + d1 * d1;
        }
        const float pr0[5] = { x0, y0, x0 * x0, y0 * y0, x0 * y0 };
        const float pr1[5] = { x1, y1, x1 * x1, y1 * y1, x1 * y1 };
        #pragma unroll
        for (int j = 0; j < OH; ++j) {
            const int k = i - j;
            if (k >= 0 && k <= 10) {
                const float w = wv[k];
                #pragma unroll
                for (int p = 0; p < 5; ++p) {
                    acc[p][j][0] = fmaf(w, pr0[p], acc[p][j][0]);
                    acc[p][j][1] = fmaf(w, pr1[p], acc[p][j][1]);
                }
            }
        }
    }

    __half* sP = reinterpret_cast<__half*>(sRaw);   // 20 rows x 512 halves
    #pragma unroll
    for (int p = 0; p < 5; ++p)
        #pragma unroll
        for (int j = 0; j < OH; ++j)
            *reinterpret_cast<__half2*>(&sP[(p * OH + j) * 512 + c0]) =
                __floats2half2_rn(acc[p][j][0], acc[p][j][1]);

    __syncthreads();

    // ------- phase B: horizontal 11-tap conv + SSIM map (8 cols/thread) -----
    const int g   = tid & 63;         // 64 col-groups
    const int r   = tid >> 6;         // row 0..3
    const int oc0 = g * 8;
    // third aligned read, clamped in-bounds (values only feed masked cols)
    const int c2  = (oc0 + 16 <= 504) ? (oc0 + 16) : 504;

    float hc[5][8];
    #pragma unroll
    for (int p = 0; p < 5; ++p) {
        const __half* rowb = &sP[(p * OH + r) * 512];
        union { float4 f4; __half h[8]; } u0, u1, u2;
        u0.f4 = *reinterpret_cast<const float4*>(rowb + oc0);
        u1.f4 = *reinterpret_cast<const float4*>(rowb + oc0 + 8);
        u2.f4 = *reinterpret_cast<const float4*>(rowb + c2);
        float win[24];
        #pragma unroll
        for (int i = 0; i < 8; ++i) {
            win[i]      = __half2float(u0.h[i]);
            win[i + 8]  = __half2float(u1.h[i]);
            win[i + 16] = __half2float(u2.h[i]);
        }
        #pragma unroll
        for (int cc = 0; cc < 8; ++cc) {
            float s = 0.f;
            #pragma unroll
            for (int dx = 0; dx < 11; ++dx)
                s = fmaf(wv[dx], win[cc + dx], s);
            hc[p][cc] = s;
        }
    }

    float ssim_acc = 0.f;
    {
        const float C1 = 0.0001f, C2 = 0.0009f;
        const int oyg = oy0 + r;
        if (oyg < 502) {
            #pragma unroll
            for (int cc = 0; cc < 8; ++cc) {
                if (oc0 + cc < 502) {
                    const float mu1 = hc[0][cc], mu2 = hc[1][cc];
                    const float m11 = mu1 * mu1, m22 = mu2 * mu2, m12 = mu1 * mu2;
                    const float s1  = hc[2][cc] - m11;
                    const float s2  = hc[3][cc] - m22;
                    const float s12 = hc[4][cc] - m12;
                    const float num = (2.f * m12 + C1) * (2.f * s12 + C2);
                    const float den = (m11 + m22 + C1) * (s1 + s2 + C2);
                    ssim_acc += num * __builtin_amdgcn_rcpf(den);
                }
            }
        }
    }

    // ---------------- reduction: wave shfl -> LDS -> 2 atomics --------------
    float vx = mse_acc, vy = ssim_acc;
    #pragma unroll
    for (int off = 32; off > 0; off >>= 1) {
        vx += __shfl_down(vx, off);
        vy += __shfl_down(vy, off);
    }
    __syncthreads();                     // phase-B LDS reads done; reuse sRaw
    const int wave = tid >> 6;
    if ((tid & 63) == 0) { sRaw[wave * 2] = vx; sRaw[wave * 2 + 1] = vy; }
    __syncthreads();
    if (tid == 0) {
        atomicAdd(&accum[0], sRaw[0] + sRaw[2] + sRaw[4] + sRaw[6]);
        atomicAdd(&accum[1], sRaw[1] + sRaw[3] + sRaw[5] + sRaw[7]);
    }
}

__global__ void ssim_finalize(const float* __restrict__ acc, float* __restrict__ out)
{
    // N_mse = 16*3*512*512 = 12582912 ; N_ssim = 16*3*502*502 = 12096192
    const float mse  = acc[0] * (1.0f / 12582912.0f);
    const float ssim = acc[1] * (1.0f / 12096192.0f);
    out[0] = 0.16f * mse + 0.84f * (1.0f - ssim);
}

extern "C" void kernel_launch(void* const* d_in, const int* in_sizes, int n_in,
                              void* d_out, int out_size, void* d_ws, size_t ws_size,
                              hipStream_t stream)
{
    const float* pred = (const float*)d_in[0];
    const float* targ = (const float*)d_in[1];
    float* ws = (float*)d_ws;

    hipMemsetAsync(ws, 0, 2 * sizeof(float), stream);
    // 48 planes * 128 row-strips = 6144 blocks
    ssim_fused<<<6144, 256, 0, stream>>>(pred, targ, ws);
    ssim_finalize<<<1, 1, 0, stream>>>(ws, (float*)d_out);
}

// Round 7
// 68.182 us; speedup vs baseline: 2.5668x; 2.5668x over previous
//
#include <hip/hip_runtime.h>
#include <hip/hip_fp16.h>

// Composite loss: 0.16*MSE + 0.84*(1-SSIM), 16x3x512x512 f32, win=11 sigma=1.5
// Vertical-first streaming with ASYNC global->LDS staging.
// R7 change: NO global atomics — each block stores partials to a unique
// d_ws slot; a second kernel reduces 6144 float2 partials to the scalar.
// (R1-R6 evidence: dur == 27ns * nblocks == atomic-serialization floor.)

#define OH 4

__device__ __forceinline__ void gload16(const float* g, float* l)
{
    __builtin_amdgcn_global_load_lds(
        (const __attribute__((address_space(1))) void*)g,
        (__attribute__((address_space(3))) void*)l,
        16, 0, 0);
}

__global__ __launch_bounds__(256, 2) void ssim_fused(
    const float* __restrict__ pred, const float* __restrict__ targ,
    float2* __restrict__ part)
{
    __shared__ float sRaw[2 * 14 * 512];   // 57344 B; fp16 planes alias front

    // Normalized 11-tap Gaussian (sigma=1.5)
    const float wv[11] = {
        0.00102838f, 0.00759876f, 0.03600078f, 0.10936070f, 0.21300554f,
        0.26601173f,
        0.21300554f, 0.10936070f, 0.03600078f, 0.00759876f, 0.00102838f };

    const int tid = threadIdx.x;
    // XCD-aware swizzle: 6144 blocks = 8 XCDs * 768 contiguous (bijective)
    const int bid = ((int)blockIdx.x & 7) * 768 + ((int)blockIdx.x >> 3);
    const int img = bid >> 7;             // 48 planes
    const int oy0 = (bid & 127) * OH;     // 128 row-strips
    const float* __restrict__ P = pred + (size_t)img * (512 * 512);
    const float* __restrict__ T = targ + (size_t)img * (512 * 512);

    // ---------------- async stage: 14 rows x {P,T} -> LDS -------------------
    {
        const int lane = tid & 63;
        const int w    = tid >> 6;        // wave 0..3
        const int half = w & 1;           // which 1KB half-row
        const int tens = w >> 1;          // 0: pred, 1: targ
        const float* gsrc = tens ? T : P;
        float* lbase = sRaw + tens * (14 * 512);
        #pragma unroll
        for (int k = 0; k < 14; ++k) {
            int gy = oy0 + k; if (gy > 511) gy = 511;   // clamped rows feed only masked outputs
            gload16(gsrc + gy * 512 + half * 256 + lane * 4,
                    lbase + k * 512 + half * 256);
        }
    }
    asm volatile("s_waitcnt vmcnt(0)" ::: "memory");
    __syncthreads();

    // ---------------- phase A: bulk LDS->reg, then vertical conv ------------
    const int c0 = tid * 2;

    float2 xr[14], yr[14];
    #pragma unroll
    for (int i = 0; i < 14; ++i) {
        xr[i] = *reinterpret_cast<const float2*>(sRaw + i * 512 + c0);
        yr[i] = *reinterpret_cast<const float2*>(sRaw + (14 + i) * 512 + c0);
    }
    __syncthreads();   // all raw reads done; planes may overwrite staging

    float acc[5][OH][2];
    #pragma unroll
    for (int p = 0; p < 5; ++p)
        #pragma unroll
        for (int j = 0; j < OH; ++j) { acc[p][j][0] = 0.f; acc[p][j][1] = 0.f; }

    float mse_acc = 0.f;

    #pragma unroll
    for (int i = 0; i < 14; ++i) {
        const float x0 = fminf(fmaxf(xr[i].x, 0.f), 1.f);
        const float x1 = fminf(fmaxf(xr[i].y, 0.f), 1.f);
        const float y0 = fminf(fmaxf(yr[i].x, 0.f), 1.f);
        const float y1 = fminf(fmaxf(yr[i].y, 0.f), 1.f);
        if (i < OH) {   // this block's disjoint MSE rows
            const float d0 = x0 - y0, d1 = x1 - y1;
            mse_acc += d0 * d0 + d1 * d1;
        }
        const float pr0[5] = { x0, y0, x0 * x0, y0 * y0, x0 * y0 };
        const float pr1[5] = { x1, y1, x1 * x1, y1 * y1, x1 * y1 };
        #pragma unroll
        for (int j = 0; j < OH; ++j) {
            const int k = i - j;
            if (k >= 0 && k <= 10) {
                const float w = wv[k];
                #pragma unroll
                for (int p = 0; p < 5; ++p) {
                    acc[p][j][0] = fmaf(w, pr0[p], acc[p][j][0]);
                    acc[p][j][1] = fmaf(w, pr1[p], acc[p][j][1]);
                }
            }
        }
    }

    __half* sP = reinterpret_cast<__half*>(sRaw);   // 20 rows x 512 halves
    #pragma unroll
    for (int p = 0; p < 5; ++p)
        #pragma unroll
        for (int j = 0; j < OH; ++j)
            *reinterpret_cast<__half2*>(&sP[(p * OH + j) * 512 + c0]) =
                __floats2half2_rn(acc[p][j][0], acc[p][j][1]);

    __syncthreads();

    // ------- phase B: horizontal 11-tap conv + SSIM map (8 cols/thread) -----
    const int g   = tid & 63;         // 64 col-groups
    const int r   = tid >> 6;         // row 0..3
    const int oc0 = g * 8;
    // third aligned read, clamped in-bounds (values only feed masked cols)
    const int c2  = (oc0 + 16 <= 504) ? (oc0 + 16) : 504;

    float hc[5][8];
    #pragma unroll
    for (int p = 0; p < 5; ++p) {
        const __half* rowb = &sP[(p * OH + r) * 512];
        union { float4 f4; __half h[8]; } u0, u1, u2;
        u0.f4 = *reinterpret_cast<const float4*>(rowb + oc0);
        u1.f4 = *reinterpret_cast<const float4*>(rowb + oc0 + 8);
        u2.f4 = *reinterpret_cast<const float4*>(rowb + c2);
        float win[24];
        #pragma unroll
        for (int i = 0; i < 8; ++i) {
            win[i]      = __half2float(u0.h[i]);
            win[i + 8]  = __half2float(u1.h[i]);
            win[i + 16] = __half2float(u2.h[i]);
        }
        #pragma unroll
        for (int cc = 0; cc < 8; ++cc) {
            float s = 0.f;
            #pragma unroll
            for (int dx = 0; dx < 11; ++dx)
                s = fmaf(wv[dx], win[cc + dx], s);
            hc[p][cc] = s;
        }
    }

    float ssim_acc = 0.f;
    {
        const float C1 = 0.0001f, C2 = 0.0009f;
        const int oyg = oy0 + r;
        if (oyg < 502) {
            #pragma unroll
            for (int cc = 0; cc < 8; ++cc) {
                if (oc0 + cc < 502) {
                    const float mu1 = hc[0][cc], mu2 = hc[1][cc];
                    const float m11 = mu1 * mu1, m22 = mu2 * mu2, m12 = mu1 * mu2;
                    const float s1  = hc[2][cc] - m11;
                    const float s2  = hc[3][cc] - m22;
                    const float s12 = hc[4][cc] - m12;
                    const float num = (2.f * m12 + C1) * (2.f * s12 + C2);
                    const float den = (m11 + m22 + C1) * (s1 + s2 + C2);
                    ssim_acc += num * __builtin_amdgcn_rcpf(den);
                }
            }
        }
    }

    // -------- block reduction: wave shfl -> LDS -> ONE store per block ------
    float vx = mse_acc, vy = ssim_acc;
    #pragma unroll
    for (int off = 32; off > 0; off >>= 1) {
        vx += __shfl_down(vx, off);
        vy += __shfl_down(vy, off);
    }
    __syncthreads();                     // phase-B LDS reads done; reuse sRaw
    const int wave = tid >> 6;
    if ((tid & 63) == 0) { sRaw[wave * 2] = vx; sRaw[wave * 2 + 1] = vy; }
    __syncthreads();
    if (tid == 0) {
        part[bid] = make_float2(sRaw[0] + sRaw[2] + sRaw[4] + sRaw[6],
                                sRaw[1] + sRaw[3] + sRaw[5] + sRaw[7]);
    }
}

__global__ __launch_bounds__(256) void ssim_reduce(
    const float2* __restrict__ part, float* __restrict__ out)
{
    __shared__ float red[8];
    const int tid = threadIdx.x;
    float ms = 0.f, ss = 0.f;
    for (int i = tid; i < 6144; i += 256) {
        const float2 v = part[i];
        ms += v.x; ss += v.y;
    }
    #pragma unroll
    for (int off = 32; off > 0; off >>= 1) {
        ms += __shfl_down(ms, off);
        ss += __shfl_down(ss, off);
    }
    const int wave = tid >> 6;
    if ((tid & 63) == 0) { red[wave * 2] = ms; red[wave * 2 + 1] = ss; }
    __syncthreads();
    if (tid == 0) {
        const float msum = red[0] + red[2] + red[4] + red[6];
        const float ssum = red[1] + red[3] + red[5] + red[7];
        // N_mse = 16*3*512*512 = 12582912 ; N_ssim = 16*3*502*502 = 12096192
        const float mse  = msum * (1.0f / 12582912.0f);
        const float ssim = ssum * (1.0f / 12096192.0f);
        out[0] = 0.16f * mse + 0.84f * (1.0f - ssim);
    }
}

extern "C" void kernel_launch(void* const* d_in, const int* in_sizes, int n_in,
                              void* d_out, int out_size, void* d_ws, size_t ws_size,
                              hipStream_t stream)
{
    const float* pred = (const float*)d_in[0];
    const float* targ = (const float*)d_in[1];
    float2* part = (float2*)d_ws;      // 6144 * 8 B = 48 KiB, fully rewritten
                                       // every launch (poison-safe)

    // 48 planes * 128 row-strips = 6144 blocks
    ssim_fused<<<6144, 256, 0, stream>>>(pred, targ, part);
    ssim_reduce<<<1, 256, 0, stream>>>(part, (float*)d_out);
}

// Round 8
// 60.722 us; speedup vs baseline: 2.8821x; 1.1228x over previous
//
#include <hip/hip_runtime.h>
#include <hip/hip_fp16.h>

// Composite loss: 0.16*MSE + 0.84*(1-SSIM), 16x3x512x512 f32, win=11 sigma=1.5
// R8: packed-fp16 (v_pk_fma_f16) convolutions, both passes alignment-free:
//   phase A packs col-pairs (conv over rows), repacks 2x2 -> row-pair planes
//   phase B packs row-pairs (conv over cols), all taps aligned half2
// Async global->LDS fp32 staging (R6) + per-block partial stores (R7) kept.

#define OH 4

__device__ __forceinline__ void gload16(const float* g, float* l)
{
    __builtin_amdgcn_global_load_lds(
        (const __attribute__((address_space(1))) void*)g,
        (__attribute__((address_space(3))) void*)l,
        16, 0, 0);
}

__global__ __launch_bounds__(256, 2) void ssim_fused(
    const float* __restrict__ pred, const float* __restrict__ targ,
    float2* __restrict__ part)
{
    __shared__ float sRaw[2 * 14 * 512];   // 57344 B; fp16 planes alias front

    // Normalized 11-tap Gaussian (sigma=1.5)
    const float wv[11] = {
        0.00102838f, 0.00759876f, 0.03600078f, 0.10936070f, 0.21300554f,
        0.26601173f,
        0.21300554f, 0.10936070f, 0.03600078f, 0.00759876f, 0.00102838f };
    __half2 wh[11];
    #pragma unroll
    for (int k = 0; k < 11; ++k) wh[k] = __float2half2_rn(wv[k]);

    const int tid = threadIdx.x;
    // XCD-aware swizzle: 6144 blocks = 8 XCDs * 768 contiguous (bijective)
    const int bid = ((int)blockIdx.x & 7) * 768 + ((int)blockIdx.x >> 3);
    const int img = bid >> 7;             // 48 planes
    const int oy0 = (bid & 127) * OH;     // 128 row-strips
    const float* __restrict__ P = pred + (size_t)img * (512 * 512);
    const float* __restrict__ T = targ + (size_t)img * (512 * 512);

    // ---------------- async stage: 14 rows x {P,T} -> LDS -------------------
    {
        const int lane = tid & 63;
        const int w    = tid >> 6;        // wave 0..3
        const int half = w & 1;           // which 1KB half-row
        const int tens = w >> 1;          // 0: pred, 1: targ
        const float* gsrc = tens ? T : P;
        float* lbase = sRaw + tens * (14 * 512);
        #pragma unroll
        for (int k = 0; k < 14; ++k) {
            int gy = oy0 + k; if (gy > 511) gy = 511;   // clamped rows feed only masked outputs
            gload16(gsrc + gy * 512 + half * 256 + lane * 4,
                    lbase + k * 512 + half * 256);
        }
    }
    asm volatile("s_waitcnt vmcnt(0)" ::: "memory");
    __syncthreads();

    // ---------------- phase A: bulk LDS->reg, vertical conv (pk fp16) -------
    const int c0 = tid * 2;

    float2 xr[14], yr[14];
    #pragma unroll
    for (int i = 0; i < 14; ++i) {
        xr[i] = *reinterpret_cast<const float2*>(sRaw + i * 512 + c0);
        yr[i] = *reinterpret_cast<const float2*>(sRaw + (14 + i) * 512 + c0);
    }
    __syncthreads();   // all raw reads done; planes may overwrite staging

    __half2 va[5][OH];               // packed col-pair accumulators
    #pragma unroll
    for (int p = 0; p < 5; ++p)
        #pragma unroll
        for (int j = 0; j < OH; ++j) va[p][j] = __float2half2_rn(0.0f);

    float mse_acc = 0.f;

    #pragma unroll
    for (int i = 0; i < 14; ++i) {
        const float x0 = fminf(fmaxf(xr[i].x, 0.f), 1.f);
        const float x1 = fminf(fmaxf(xr[i].y, 0.f), 1.f);
        const float y0 = fminf(fmaxf(yr[i].x, 0.f), 1.f);
        const float y1 = fminf(fmaxf(yr[i].y, 0.f), 1.f);
        if (i < OH) {   // this block's disjoint MSE rows (fp32)
            const float d0 = x0 - y0, d1 = x1 - y1;
            mse_acc += d0 * d0 + d1 * d1;
        }
        const __half2 hx = __halves2half2(__float2half_rn(x0), __float2half_rn(x1));
        const __half2 hy = __halves2half2(__float2half_rn(y0), __float2half_rn(y1));
        const __half2 pr[5] = { hx, hy, __hmul2(hx, hx), __hmul2(hy, hy),
                                __hmul2(hx, hy) };
        #pragma unroll
        for (int j = 0; j < OH; ++j) {
            const int k = i - j;
            if (k >= 0 && k <= 10) {
                #pragma unroll
                for (int p = 0; p < 5; ++p)
                    va[p][j] = __hfma2(wh[k], pr[p], va[p][j]);
            }
        }
    }

    // repack 2x2: col-pair regs -> row-pair planes sP[plane][rowpair][col]
    __half2* sPh2 = reinterpret_cast<__half2*>(sRaw);   // 5*2*512 half2 = 20480 B
    #pragma unroll
    for (int p = 0; p < 5; ++p)
        #pragma unroll
        for (int jp = 0; jp < 2; ++jp) {
            const __half2 a = va[p][2 * jp], b = va[p][2 * jp + 1];
            const int idx = (p * 2 + jp) * 512 + c0;
            sPh2[idx]     = __halves2half2(__low2half(a),  __low2half(b));
            sPh2[idx + 1] = __halves2half2(__high2half(a), __high2half(b));
        }

    __syncthreads();

    // ------- phase B: horizontal conv (pk fp16, row-pair) + SSIM map --------
    const int rp  = tid >> 7;         // row-pair 0..1 (rows 2rp, 2rp+1)
    const int gg  = tid & 127;        // 128 col-groups
    const int oc0 = gg * 4;           // 4 output cols/thread

    __half2 hc[5][4];
    union U { float4 f4; float2 f2; __half2 h2[4]; };
    #pragma unroll
    for (int p = 0; p < 5; ++p) {
        const __half2* base = sPh2 + (p * 2 + rp) * 512 + oc0;
        __half2 win[14];
        U u0, u1, u2, u3;
        u0.f4 = *reinterpret_cast<const float4*>(base);
        u1.f4 = *reinterpret_cast<const float4*>(base + 4);
        u2.f4 = *reinterpret_cast<const float4*>(base + 8);
        u3.f2 = *reinterpret_cast<const float2*>(base + 12);
        #pragma unroll
        for (int q = 0; q < 4; ++q) {
            win[q]     = u0.h2[q];
            win[q + 4] = u1.h2[q];
            win[q + 8] = u2.h2[q];
        }
        win[12] = u3.h2[0]; win[13] = u3.h2[1];
        #pragma unroll
        for (int cc = 0; cc < 4; ++cc) {
            __half2 s = __float2half2_rn(0.0f);
            #pragma unroll
            for (int t = 0; t < 11; ++t)
                s = __hfma2(wh[t], win[cc + t], s);
            hc[p][cc] = s;
        }
    }

    float ssim_acc = 0.f;
    {
        const float C1 = 0.0001f, C2 = 0.0009f;
        const int ylo = oy0 + 2 * rp;
        const bool vlo = ylo < 502, vhi = (ylo + 1) < 502;
        #pragma unroll
        for (int cc = 0; cc < 4; ++cc) {
            if (oc0 + cc < 502) {
                #pragma unroll
                for (int h = 0; h < 2; ++h) {
                    if (h ? vhi : vlo) {
                        const float mu1 = h ? __high2float(hc[0][cc]) : __low2float(hc[0][cc]);
                        const float mu2 = h ? __high2float(hc[1][cc]) : __low2float(hc[1][cc]);
                        const float exx = h ? __high2float(hc[2][cc]) : __low2float(hc[2][cc]);
                        const float eyy = h ? __high2float(hc[3][cc]) : __low2float(hc[3][cc]);
                        const float exy = h ? __high2float(hc[4][cc]) : __low2float(hc[4][cc]);
                        const float m11 = mu1 * mu1, m22 = mu2 * mu2, m12 = mu1 * mu2;
                        const float s1  = exx - m11;
                        const float s2  = eyy - m22;
                        const float s12 = exy - m12;
                        const float num = (2.f * m12 + C1) * (2.f * s12 + C2);
                        const float den = (m11 + m22 + C1) * (s1 + s2 + C2);
                        ssim_acc += num * __builtin_amdgcn_rcpf(den);
                    }
                }
            }
        }
    }

    // -------- block reduction: wave shfl -> LDS -> ONE store per block ------
    float vx = mse_acc, vy = ssim_acc;
    #pragma unroll
    for (int off = 32; off > 0; off >>= 1) {
        vx += __shfl_down(vx, off);
        vy += __shfl_down(vy, off);
    }
    __syncthreads();                     // phase-B LDS reads done; reuse sRaw
    const int wave = tid >> 6;
    if ((tid & 63) == 0) { sRaw[wave * 2] = vx; sRaw[wave * 2 + 1] = vy; }
    __syncthreads();
    if (tid == 0) {
        part[bid] = make_float2(sRaw[0] + sRaw[2] + sRaw[4] + sRaw[6],
                                sRaw[1] + sRaw[3] + sRaw[5] + sRaw[7]);
    }
}

__global__ __launch_bounds__(256) void ssim_reduce(
    const float2* __restrict__ part, float* __restrict__ out)
{
    __shared__ float red[8];
    const int tid = threadIdx.x;
    float ms = 0.f, ss = 0.f;
    for (int i = tid; i < 6144; i += 256) {
        const float2 v = part[i];
        ms += v.x; ss += v.y;
    }
    #pragma unroll
    for (int off = 32; off > 0; off >>= 1) {
        ms += __shfl_down(ms, off);
        ss += __shfl_down(ss, off);
    }
    const int wave = tid >> 6;
    if ((tid & 63) == 0) { red[wave * 2] = ms; red[wave * 2 + 1] = ss; }
    __syncthreads();
    if (tid == 0) {
        const float msum = red[0] + red[2] + red[4] + red[6];
        const float ssum = red[1] + red[3] + red[5] + red[7];
        // N_mse = 16*3*512*512 = 12582912 ; N_ssim = 16*3*502*502 = 12096192
        const float mse  = msum * (1.0f / 12582912.0f);
        const float ssim = ssum * (1.0f / 12096192.0f);
        out[0] = 0.16f * mse + 0.84f * (1.0f - ssim);
    }
}

extern "C" void kernel_launch(void* const* d_in, const int* in_sizes, int n_in,
                              void* d_out, int out_size, void* d_ws, size_t ws_size,
                              hipStream_t stream)
{
    const float* pred = (const float*)d_in[0];
    const float* targ = (const float*)d_in[1];
    float2* part = (float2*)d_ws;      // 6144 * 8 B, fully rewritten each launch

    // 48 planes * 128 row-strips = 6144 blocks
    ssim_fused<<<6144, 256, 0, stream>>>(pred, targ, part);
    ssim_reduce<<<1, 256, 0, stream>>>(part, (float*)d_out);
}

// Round 9
// 50.246 us; speedup vs baseline: 3.4831x; 1.2085x over previous
//
#include <hip/hip_runtime.h>
#include <hip/hip_fp16.h>

// Composite loss: 0.16*MSE + 0.84*(1-SSIM), 16x3x512x512 f32, win=11 sigma=1.5
// R9: drop raw-LDS staging (R7 showed R4's "load chain" was really the atomic
// floor). Phase A streams float2 directly from global (L2/L3-hot), LDS holds
// only the 20480B fp16 planes -> ~5 blocks/CU instead of 2.
//   phase A: per-thread 2 cols, stream 14 rows, pk-fp16 vertical conv,
//            2x2 repack -> row-pair planes in LDS
//   phase B: pk-fp16 horizontal conv on row-pairs + SSIM map (fp32)
//   reduce:  per-block partial -> d_ws slot; second kernel folds 6144 slots.

#define OH 4

__global__ __launch_bounds__(256, 4) void ssim_fused(
    const float* __restrict__ pred, const float* __restrict__ targ,
    float2* __restrict__ part)
{
    __shared__ __half2 sPh2[5 * 2 * 512];   // 20480 B (planes, row-pair packed)

    // Normalized 11-tap Gaussian (sigma=1.5)
    const float wv[11] = {
        0.00102838f, 0.00759876f, 0.03600078f, 0.10936070f, 0.21300554f,
        0.26601173f,
        0.21300554f, 0.10936070f, 0.03600078f, 0.00759876f, 0.00102838f };
    __half2 wh[11];
    #pragma unroll
    for (int k = 0; k < 11; ++k) wh[k] = __float2half2_rn(wv[k]);

    const int tid = threadIdx.x;
    // XCD-aware swizzle: 6144 blocks = 8 XCDs * 768 contiguous (bijective)
    const int bid = ((int)blockIdx.x & 7) * 768 + ((int)blockIdx.x >> 3);
    const int img = bid >> 7;             // 48 planes
    const int oy0 = (bid & 127) * OH;     // 128 row-strips
    const float* __restrict__ P = pred + (size_t)img * (512 * 512);
    const float* __restrict__ T = targ + (size_t)img * (512 * 512);

    // ---------------- phase A: stream rows, pk-fp16 vertical conv -----------
    const int c0 = tid * 2;

    __half2 va[5][OH];               // packed col-pair accumulators
    #pragma unroll
    for (int p = 0; p < 5; ++p)
        #pragma unroll
        for (int j = 0; j < OH; ++j) va[p][j] = __float2half2_rn(0.0f);

    float mse_acc = 0.f;

    #pragma unroll
    for (int i = 0; i < 14; ++i) {
        int gy = oy0 + i; if (gy > 511) gy = 511;   // clamped rows feed only masked outputs
        const float2 xv = *reinterpret_cast<const float2*>(P + gy * 512 + c0);
        const float2 yv = *reinterpret_cast<const float2*>(T + gy * 512 + c0);
        const float x0 = fminf(fmaxf(xv.x, 0.f), 1.f);
        const float x1 = fminf(fmaxf(xv.y, 0.f), 1.f);
        const float y0 = fminf(fmaxf(yv.x, 0.f), 1.f);
        const float y1 = fminf(fmaxf(yv.y, 0.f), 1.f);
        if (i < OH) {   // this block's disjoint MSE rows (fp32)
            const float d0 = x0 - y0, d1 = x1 - y1;
            mse_acc += d0 * d0 + d1 * d1;
        }
        const __half2 hx = __halves2half2(__float2half_rn(x0), __float2half_rn(x1));
        const __half2 hy = __halves2half2(__float2half_rn(y0), __float2half_rn(y1));
        const __half2 pr[5] = { hx, hy, __hmul2(hx, hx), __hmul2(hy, hy),
                                __hmul2(hx, hy) };
        #pragma unroll
        for (int j = 0; j < OH; ++j) {
            const int k = i - j;
            if (k >= 0 && k <= 10) {
                #pragma unroll
                for (int p = 0; p < 5; ++p)
                    va[p][j] = __hfma2(wh[k], pr[p], va[p][j]);
            }
        }
    }

    // repack 2x2: col-pair regs -> row-pair planes sPh2[plane][rowpair][col]
    #pragma unroll
    for (int p = 0; p < 5; ++p)
        #pragma unroll
        for (int jp = 0; jp < 2; ++jp) {
            const __half2 a = va[p][2 * jp], b = va[p][2 * jp + 1];
            const int idx = (p * 2 + jp) * 512 + c0;
            sPh2[idx]     = __halves2half2(__low2half(a),  __low2half(b));
            sPh2[idx + 1] = __halves2half2(__high2half(a), __high2half(b));
        }

    __syncthreads();

    // ------- phase B: horizontal conv (pk fp16, row-pair) + SSIM map --------
    const int rp  = tid >> 7;         // row-pair 0..1 (rows 2rp, 2rp+1)
    const int gg  = tid & 127;        // 128 col-groups
    const int oc0 = gg * 4;           // 4 output cols/thread

    __half2 hc[5][4];
    union U { float4 f4; float2 f2; __half2 h2[4]; };
    #pragma unroll
    for (int p = 0; p < 5; ++p) {
        const __half2* base = sPh2 + (p * 2 + rp) * 512 + oc0;
        __half2 win[14];
        U u0, u1, u2, u3;
        u0.f4 = *reinterpret_cast<const float4*>(base);
        u1.f4 = *reinterpret_cast<const float4*>(base + 4);
        u2.f4 = *reinterpret_cast<const float4*>(base + 8);
        u3.f2 = *reinterpret_cast<const float2*>(base + 12);
        #pragma unroll
        for (int q = 0; q < 4; ++q) {
            win[q]     = u0.h2[q];
            win[q + 4] = u1.h2[q];
            win[q + 8] = u2.h2[q];
        }
        win[12] = u3.h2[0]; win[13] = u3.h2[1];
        #pragma unroll
        for (int cc = 0; cc < 4; ++cc) {
            __half2 s = __float2half2_rn(0.0f);
            #pragma unroll
            for (int t = 0; t < 11; ++t)
                s = __hfma2(wh[t], win[cc + t], s);
            hc[p][cc] = s;
        }
    }

    float ssim_acc = 0.f;
    {
        const float C1 = 0.0001f, C2 = 0.0009f;
        const int ylo = oy0 + 2 * rp;
        const bool vlo = ylo < 502, vhi = (ylo + 1) < 502;
        #pragma unroll
        for (int cc = 0; cc < 4; ++cc) {
            if (oc0 + cc < 502) {
                #pragma unroll
                for (int h = 0; h < 2; ++h) {
                    if (h ? vhi : vlo) {
                        const float mu1 = h ? __high2float(hc[0][cc]) : __low2float(hc[0][cc]);
                        const float mu2 = h ? __high2float(hc[1][cc]) : __low2float(hc[1][cc]);
                        const float exx = h ? __high2float(hc[2][cc]) : __low2float(hc[2][cc]);
                        const float eyy = h ? __high2float(hc[3][cc]) : __low2float(hc[3][cc]);
                        const float exy = h ? __high2float(hc[4][cc]) : __low2float(hc[4][cc]);
                        const float m11 = mu1 * mu1, m22 = mu2 * mu2, m12 = mu1 * mu2;
                        const float s1  = exx - m11;
                        const float s2  = eyy - m22;
                        const float s12 = exy - m12;
                        const float num = (2.f * m12 + C1) * (2.f * s12 + C2);
                        const float den = (m11 + m22 + C1) * (s1 + s2 + C2);
                        ssim_acc += num * __builtin_amdgcn_rcpf(den);
                    }
                }
            }
        }
    }

    // -------- block reduction: wave shfl -> LDS -> ONE store per block ------
    float vx = mse_acc, vy = ssim_acc;
    #pragma unroll
    for (int off = 32; off > 0; off >>= 1) {
        vx += __shfl_down(vx, off);
        vy += __shfl_down(vy, off);
    }
    __syncthreads();                     // phase-B LDS reads done; reuse sPh2
    float* redf = reinterpret_cast<float*>(sPh2);
    const int wave = tid >> 6;
    if ((tid & 63) == 0) { redf[wave * 2] = vx; redf[wave * 2 + 1] = vy; }
    __syncthreads();
    if (tid == 0) {
        part[bid] = make_float2(redf[0] + redf[2] + redf[4] + redf[6],
                                redf[1] + redf[3] + redf[5] + redf[7]);
    }
}

__global__ __launch_bounds__(256) void ssim_reduce(
    const float2* __restrict__ part, float* __restrict__ out)
{
    __shared__ float red[8];
    const int tid = threadIdx.x;
    float ms = 0.f, ss = 0.f;
    for (int i = tid; i < 6144; i += 256) {
        const float2 v = part[i];
        ms += v.x; ss += v.y;
    }
    #pragma unroll
    for (int off = 32; off > 0; off >>= 1) {
        ms += __shfl_down(ms, off);
        ss += __shfl_down(ss, off);
    }
    const int wave = tid >> 6;
    if ((tid & 63) == 0) { red[wave * 2] = ms; red[wave * 2 + 1] = ss; }
    __syncthreads();
    if (tid == 0) {
        const float msum = red[0] + red[2] + red[4] + red[6];
        const float ssum = red[1] + red[3] + red[5] + red[7];
        // N_mse = 16*3*512*512 = 12582912 ; N_ssim = 16*3*502*502 = 12096192
        const float mse  = msum * (1.0f / 12582912.0f);
        const float ssim = ssum * (1.0f / 12096192.0f);
        out[0] = 0.16f * mse + 0.84f * (1.0f - ssim);
    }
}

extern "C" void kernel_launch(void* const* d_in, const int* in_sizes, int n_in,
                              void* d_out, int out_size, void* d_ws, size_t ws_size,
                              hipStream_t stream)
{
    const float* pred = (const float*)d_in[0];
    const float* targ = (const float*)d_in[1];
    float2* part = (float2*)d_ws;      // 6144 * 8 B, fully rewritten each launch

    // 48 planes * 128 row-strips = 6144 blocks
    ssim_fused<<<6144, 256, 0, stream>>>(pred, targ, part);
    ssim_reduce<<<1, 256, 0, stream>>>(part, (float*)d_out);
}

// Round 10
// 43.500 us; speedup vs baseline: 4.0232x; 1.1551x over previous
//
#include <hip/hip_runtime.h>
#include <hip/hip_fp16.h>

// Composite loss: 0.16*MSE + 0.84*(1-SSIM), 16x3x512x512 f32, win=11 sigma=1.5
// R10: OH=8 strips (2.25x halo re-read vs 3.5x), med3 clamp, fused b64 plane
// stores, wave-per-row-pair phase B, float4 reduce.
//   phase A: per-thread 2 cols, stream 18 rows from global, pk-fp16 vertical
//            conv (5 planes x 8 rows), 2x2 repack -> row-pair planes in LDS
//   phase B: wave w owns row-pair w; lane owns 8 cols; pk-fp16 horizontal conv
//            + fp32 SSIM map
//   reduce:  per-block partial -> d_ws; 1-block float4 tree reduce.

#define OH 8

struct __align__(8) H2x2 { __half2 a, b; };

__global__ __launch_bounds__(256, 4) void ssim_fused(
    const float* __restrict__ pred, const float* __restrict__ targ,
    float2* __restrict__ part)
{
    __shared__ __half2 sPh2[5 * 4 * 512];   // 40960 B: [plane][rowpair][col]

    // Normalized 11-tap Gaussian (sigma=1.5)
    const float wv[11] = {
        0.00102838f, 0.00759876f, 0.03600078f, 0.10936070f, 0.21300554f,
        0.26601173f,
        0.21300554f, 0.10936070f, 0.03600078f, 0.00759876f, 0.00102838f };
    __half2 wh[11];
    #pragma unroll
    for (int k = 0; k < 11; ++k) wh[k] = __float2half2_rn(wv[k]);

    const int tid = threadIdx.x;
    // XCD-aware bijective swizzle: 3072 blocks = 8 XCDs * 384
    const int bid = ((int)blockIdx.x & 7) * 384 + ((int)blockIdx.x >> 3);
    const int img = bid >> 6;             // 48 planes
    const int oy0 = (bid & 63) * OH;      // 64 row-strips
    const float* __restrict__ P = pred + (size_t)img * (512 * 512);
    const float* __restrict__ T = targ + (size_t)img * (512 * 512);

    // ---------------- phase A: stream 18 rows, pk-fp16 vertical conv --------
    const int c0 = tid * 2;

    __half2 va[5][OH];               // packed col-pair accumulators
    #pragma unroll
    for (int p = 0; p < 5; ++p)
        #pragma unroll
        for (int j = 0; j < OH; ++j) va[p][j] = __float2half2_rn(0.0f);

    float mse_acc = 0.f;

    #pragma unroll
    for (int i = 0; i < OH + 10; ++i) {
        int gy = oy0 + i; if (gy > 511) gy = 511;   // clamped rows feed only masked outputs
        const float2 xv = *reinterpret_cast<const float2*>(P + gy * 512 + c0);
        const float2 yv = *reinterpret_cast<const float2*>(T + gy * 512 + c0);
        const float x0 = __builtin_amdgcn_fmed3f(xv.x, 0.f, 1.f);
        const float x1 = __builtin_amdgcn_fmed3f(xv.y, 0.f, 1.f);
        const float y0 = __builtin_amdgcn_fmed3f(yv.x, 0.f, 1.f);
        const float y1 = __builtin_amdgcn_fmed3f(yv.y, 0.f, 1.f);
        if (i < OH) {   // this block's disjoint MSE rows (fp32)
            const float d0 = x0 - y0, d1 = x1 - y1;
            mse_acc = fmaf(d0, d0, mse_acc);
            mse_acc = fmaf(d1, d1, mse_acc);
        }
        const __half2 hx = __float22half2_rn(make_float2(x0, x1));
        const __half2 hy = __float22half2_rn(make_float2(y0, y1));
        const __half2 pr[5] = { hx, hy, __hmul2(hx, hx), __hmul2(hy, hy),
                                __hmul2(hx, hy) };
        #pragma unroll
        for (int j = 0; j < OH; ++j) {
            const int k = i - j;
            if (k >= 0 && k <= 10) {
                #pragma unroll
                for (int p = 0; p < 5; ++p)
                    va[p][j] = __hfma2(wh[k], pr[p], va[p][j]);
            }
        }
    }

    // repack 2x2 and store both half2 as ONE 8B write:
    // sPh2[(p*4+jp)*512 + c0] = (lo(a),lo(b)) ; +1 = (hi(a),hi(b))
    #pragma unroll
    for (int p = 0; p < 5; ++p)
        #pragma unroll
        for (int jp = 0; jp < 4; ++jp) {
            const __half2 a = va[p][2 * jp], b = va[p][2 * jp + 1];
            H2x2 st;
            st.a = __halves2half2(__low2half(a),  __low2half(b));
            st.b = __halves2half2(__high2half(a), __high2half(b));
            *reinterpret_cast<H2x2*>(&sPh2[(p * 4 + jp) * 512 + c0]) = st;
        }

    __syncthreads();

    // ------- phase B: wave = row-pair, lane = 8 cols; pk-fp16 conv + map ----
    const int rp   = tid >> 6;        // row-pair 0..3 (rows 2rp, 2rp+1)
    const int lane = tid & 63;
    const int oc0  = lane * 8;        // output cols oc0..oc0+7
    // group 63 (oc0=504): all outputs masked; clamp reads in-row (mult of 4)
    const int rc0 = (oc0 > 496) ? 492 : oc0;
    const int t2  = (rc0 + 16 > 510) ? 510 : (rc0 + 16);  // trailing float2

    __half2 hc[5][8];
    union U4 { float4 f4; __half2 h2[4]; };
    union U2 { float2 f2; __half2 h2[2]; };
    #pragma unroll
    for (int p = 0; p < 5; ++p) {
        const __half2* rowb = &sPh2[(p * 4 + rp) * 512];
        __half2 win[18];
        U4 u0, u1, u2, u3; U2 u4;
        u0.f4 = *reinterpret_cast<const float4*>(rowb + rc0);
        u1.f4 = *reinterpret_cast<const float4*>(rowb + rc0 + 4);
        u2.f4 = *reinterpret_cast<const float4*>(rowb + rc0 + 8);
        u3.f4 = *reinterpret_cast<const float4*>(rowb + rc0 + 12);
        u4.f2 = *reinterpret_cast<const float2*>(rowb + t2);
        #pragma unroll
        for (int q = 0; q < 4; ++q) {
            win[q]      = u0.h2[q];
            win[q + 4]  = u1.h2[q];
            win[q + 8]  = u2.h2[q];
            win[q + 12] = u3.h2[q];
        }
        win[16] = u4.h2[0]; win[17] = u4.h2[1];
        #pragma unroll
        for (int cc = 0; cc < 8; ++cc) {
            __half2 s = __float2half2_rn(0.0f);
            #pragma unroll
            for (int t = 0; t < 11; ++t)
                s = __hfma2(wh[t], win[cc + t], s);
            hc[p][cc] = s;
        }
    }

    float ssim_acc = 0.f;
    {
        const float C1 = 0.0001f, C2 = 0.0009f;
        const int ylo = oy0 + 2 * rp;
        const bool vlo = ylo < 502, vhi = (ylo + 1) < 502;
        #pragma unroll
        for (int cc = 0; cc < 8; ++cc) {
            if (oc0 + cc < 502) {          // oc0-based: group 63 fully masked
                #pragma unroll
                for (int h = 0; h < 2; ++h) {
                    if (h ? vhi : vlo) {
                        const float mu1 = h ? __high2float(hc[0][cc]) : __low2float(hc[0][cc]);
                        const float mu2 = h ? __high2float(hc[1][cc]) : __low2float(hc[1][cc]);
                        const float exx = h ? __high2float(hc[2][cc]) : __low2float(hc[2][cc]);
                        const float eyy = h ? __high2float(hc[3][cc]) : __low2float(hc[3][cc]);
                        const float exy = h ? __high2float(hc[4][cc]) : __low2float(hc[4][cc]);
                        const float m11 = mu1 * mu1, m22 = mu2 * mu2, m12 = mu1 * mu2;
                        const float s1  = exx - m11;
                        const float s2  = eyy - m22;
                        const float s12 = exy - m12;
                        const float num = (2.f * m12 + C1) * (2.f * s12 + C2);
                        const float den = (m11 + m22 + C1) * (s1 + s2 + C2);
                        ssim_acc += num * __builtin_amdgcn_rcpf(den);
                    }
                }
            }
        }
    }

    // -------- block reduction: wave shfl -> LDS -> ONE store per block ------
    float vx = mse_acc, vy = ssim_acc;
    #pragma unroll
    for (int off = 32; off > 0; off >>= 1) {
        vx += __shfl_down(vx, off);
        vy += __shfl_down(vy, off);
    }
    __syncthreads();                     // phase-B LDS reads done; reuse sPh2
    float* redf = reinterpret_cast<float*>(sPh2);
    const int wave = tid >> 6;
    if ((tid & 63) == 0) { redf[wave * 2] = vx; redf[wave * 2 + 1] = vy; }
    __syncthreads();
    if (tid == 0) {
        part[bid] = make_float2(redf[0] + redf[2] + redf[4] + redf[6],
                                redf[1] + redf[3] + redf[5] + redf[7]);
    }
}

__global__ __launch_bounds__(256) void ssim_reduce(
    const float2* __restrict__ part, float* __restrict__ out)
{
    __shared__ float red[8];
    const int tid = threadIdx.x;
    const float4* p4 = reinterpret_cast<const float4*>(part);  // 1536 float4
    float ms = 0.f, ss = 0.f;
    #pragma unroll
    for (int k = 0; k < 6; ++k) {
        const float4 v = p4[tid + k * 256];
        ms += v.x + v.z; ss += v.y + v.w;
    }
    #pragma unroll
    for (int off = 32; off > 0; off >>= 1) {
        ms += __shfl_down(ms, off);
        ss += __shfl_down(ss, off);
    }
    const int wave = tid >> 6;
    if ((tid & 63) == 0) { red[wave * 2] = ms; red[wave * 2 + 1] = ss; }
    __syncthreads();
    if (tid == 0) {
        const float msum = red[0] + red[2] + red[4] + red[6];
        const float ssum = red[1] + red[3] + red[5] + red[7];
        // N_mse = 16*3*512*512 = 12582912 ; N_ssim = 16*3*502*502 = 12096192
        const float mse  = msum * (1.0f / 12582912.0f);
        const float ssim = ssum * (1.0f / 12096192.0f);
        out[0] = 0.16f * mse + 0.84f * (1.0f - ssim);
    }
}

extern "C" void kernel_launch(void* const* d_in, const int* in_sizes, int n_in,
                              void* d_out, int out_size, void* d_ws, size_t ws_size,
                              hipStream_t stream)
{
    const float* pred = (const float*)d_in[0];
    const float* targ = (const float*)d_in[1];
    float2* part = (float2*)d_ws;      // 3072 * 8 B, fully rewritten each launch

    // 48 planes * 64 row-strips = 3072 blocks
    ssim_fused<<<3072, 256, 0, stream>>>(pred, targ, part);
    ssim_reduce<<<1, 256, 0, stream>>>(part, (float*)d_out);
}